// Round 7
// baseline (765.561 us; speedup 1.0000x reference)
//
#include <hip/hip_runtime.h>
#include <cstdint>

// N=50000 nodes, E=1.6M edges, IN=128, H=64, OUT=32, R=8
#define HDIM 64
#define ODIM 32
#define NEG_SLOPE 0.2f
#define SCHUNK 2048

// ---------------------------------------------------------------------------
// CSR build
// ---------------------------------------------------------------------------
__global__ __launch_bounds__(256) void count_deg_kernel(
    const int* __restrict__ dst, int* __restrict__ deg, int E) {
  int e = blockIdx.x * 256 + threadIdx.x;
  if (e < E) atomicAdd(&deg[dst[e]], 1);
}

__global__ __launch_bounds__(256) void scan_p1(const int* __restrict__ deg,
                                               int* __restrict__ bsum, int n) {
  int base = blockIdx.x * SCHUNK + threadIdx.x * 8;
  int s = 0;
#pragma unroll
  for (int j = 0; j < 8; j++) {
    int i = base + j;
    if (i < n) s += deg[i];
  }
#pragma unroll
  for (int d = 1; d < 64; d <<= 1) s += __shfl_xor(s, d, 64);
  __shared__ int ws[4];
  if ((threadIdx.x & 63) == 0) ws[threadIdx.x >> 6] = s;
  __syncthreads();
  if (threadIdx.x == 0) bsum[blockIdx.x] = ws[0] + ws[1] + ws[2] + ws[3];
}

__global__ void scan_p2(int* bsum, int nb) {
  int i = threadIdx.x;
  int v = (i < nb) ? bsum[i] : 0;
  int orig = v;
#pragma unroll
  for (int d = 1; d < 64; d <<= 1) {
    int up = __shfl_up(v, d, 64);
    if (i >= d) v += up;
  }
  if (i < nb) bsum[i] = v - orig;
}

__global__ __launch_bounds__(256) void scan_p3(const int* __restrict__ deg,
                                               const int* __restrict__ bsum,
                                               int* __restrict__ row_ptr,
                                               int n) {
  int base = blockIdx.x * SCHUNK + threadIdx.x * 8;
  int vals[8];
  int s = 0;
#pragma unroll
  for (int j = 0; j < 8; j++) {
    int i = base + j;
    vals[j] = (i < n) ? deg[i] : 0;
    s += vals[j];
  }
  int lane = threadIdx.x & 63, w = threadIdx.x >> 6;
  int v = s;
#pragma unroll
  for (int d = 1; d < 64; d <<= 1) {
    int up = __shfl_up(v, d, 64);
    if (lane >= d) v += up;
  }
  __shared__ int wsum[4];
  if (lane == 63) wsum[w] = v;
  __syncthreads();
  int woff = 0;
#pragma unroll
  for (int i = 0; i < 4; i++) woff += (i < w) ? wsum[i] : 0;
  int off = bsum[blockIdx.x] + woff + v - s;
#pragma unroll
  for (int j = 0; j < 8; j++) {
    int i = base + j;
    off += vals[j];
    if (i < n) row_ptr[i + 1] = off;
  }
  if (blockIdx.x == 0 && threadIdx.x == 0) row_ptr[0] = 0;
}

__global__ __launch_bounds__(256) void scatter_kernel(
    const int* __restrict__ src, const int* __restrict__ dst,
    const int* __restrict__ etype, const int* __restrict__ row_ptr,
    int* __restrict__ fill, int* __restrict__ edges, int E) {
  int e = blockIdx.x * 256 + threadIdx.x;
  if (e < E) {
    int d = dst[e];
    int pos = row_ptr[d] + atomicAdd(&fill[d], 1);
    edges[pos] = src[e] | (etype[e] << 16);  // N < 65536
  }
}

// ---------------------------------------------------------------------------
// Layer-1 transform (round-3 validated KC=32 version, verbatim):
// t[r,n,:] = f[n,:] @ W[r]  (+ fused aq/ak epilogue)
// ---------------------------------------------------------------------------
template <int CIN>
__global__ __launch_bounds__(256) void transform_kernel(
    const float* __restrict__ f, const float* __restrict__ W,
    const float* __restrict__ q, const float* __restrict__ k,
    float* __restrict__ t, float* __restrict__ aq, float* __restrict__ ak,
    int N) {
  constexpr int KC = 32;
  constexpr int FLD = 260;
  constexpr int WLD = 68;
  __shared__ float Fl[KC * FLD];
  __shared__ float Wl[KC * WLD];

  const int r = blockIdx.x;
  const int n0 = blockIdx.y * 256;
  const int tid = threadIdx.x;
  const int nt = tid >> 3;
  const int ot = tid & 7;
  const int on0 = ot * 8;

  float acc[8][8];
#pragma unroll
  for (int i = 0; i < 8; i++)
#pragma unroll
    for (int j = 0; j < 8; j++) acc[i][j] = 0.f;

  for (int k0 = 0; k0 < CIN; k0 += KC) {
    {
      const int kk = (tid & 7) * 4;
      const int nb = tid >> 3;
#pragma unroll
      for (int i = 0; i < 8; i++) {
        const int n = nb + i * 32;
        const int gn = n0 + n;
        float4 v = make_float4(0.f, 0.f, 0.f, 0.f);
        if (gn < N) v = *(const float4*)&f[(size_t)gn * CIN + k0 + kk];
        Fl[(kk + 0) * FLD + n] = v.x;
        Fl[(kk + 1) * FLD + n] = v.y;
        Fl[(kk + 2) * FLD + n] = v.z;
        Fl[(kk + 3) * FLD + n] = v.w;
      }
    }
    {
      const int oc = (tid & 15) * 4;
#pragma unroll
      for (int i = 0; i < 2; i++) {
        const int kr = (tid >> 4) + i * 16;
        float4 v = *(const float4*)&W[((size_t)r * CIN + k0 + kr) * 64 + oc];
        *(float4*)&Wl[kr * WLD + oc] = v;
      }
    }
    __syncthreads();

#pragma unroll 4
    for (int kk = 0; kk < KC; kk++) {
      float4 fA = *(const float4*)&Fl[kk * FLD + nt * 8];
      float4 fB = *(const float4*)&Fl[kk * FLD + nt * 8 + 4];
      float4 wA = *(const float4*)&Wl[kk * WLD + on0];
      float4 wB = *(const float4*)&Wl[kk * WLD + on0 + 4];
      float fv[8] = {fA.x, fA.y, fA.z, fA.w, fB.x, fB.y, fB.z, fB.w};
      float wv[8] = {wA.x, wA.y, wA.z, wA.w, wB.x, wB.y, wB.z, wB.w};
#pragma unroll
      for (int i = 0; i < 8; i++)
#pragma unroll
        for (int j = 0; j < 8; j++) acc[i][j] = fmaf(fv[i], wv[j], acc[i][j]);
    }
    __syncthreads();
  }

  float qv[8], kv[8];
#pragma unroll
  for (int j = 0; j < 8; j++) {
    qv[j] = q[on0 + j];
    kv[j] = k[on0 + j];
  }

#pragma unroll
  for (int i = 0; i < 8; i++) {
    const int gn = n0 + nt * 8 + i;
    const bool valid = gn < N;
    if (valid) {
      float* dst = &t[((size_t)r * N + gn) * 64 + on0];
      *(float4*)dst = make_float4(acc[i][0], acc[i][1], acc[i][2], acc[i][3]);
      *(float4*)(dst + 4) =
          make_float4(acc[i][4], acc[i][5], acc[i][6], acc[i][7]);
    }
    float vq = 0.f, vk = 0.f;
#pragma unroll
    for (int j = 0; j < 8; j++) {
      vq = fmaf(acc[i][j], qv[j], vq);
      vk = fmaf(acc[i][j], kv[j], vk);
    }
#pragma unroll
    for (int d = 1; d < 8; d <<= 1) {
      vq += __shfl_xor(vq, d, 64);
      vk += __shfl_xor(vk, d, 64);
    }
    if (ot == 0 && valid) {
      aq[(size_t)r * N + gn] = vq;
      ak[(size_t)r * N + gn] = vk;
    }
  }
}

// ---------------------------------------------------------------------------
// Fused mu+lv transform (round-3 validated KC=32 version, verbatim).
// t2: [R][N][2][64]; aq2/ak2: [(mat*8+r)][N].
// ---------------------------------------------------------------------------
__global__ __launch_bounds__(256) void transform2_kernel(
    const float* __restrict__ f, const float* __restrict__ Wa,
    const float* __restrict__ Wb, const float* __restrict__ qa,
    const float* __restrict__ ka, const float* __restrict__ qb,
    const float* __restrict__ kb, float* __restrict__ t2,
    float* __restrict__ aq2, float* __restrict__ ak2, int N) {
  constexpr int CIN = 64, KC = 32;
  constexpr int FLD = 132;  // 128 + 4 pad
  constexpr int WLD = 68;
  __shared__ float Fl[KC * FLD];
  __shared__ float Wl[2][KC * WLD + 4];  // +4: offsets mat1 banks by 4

  const int r = blockIdx.x;
  const int n0 = blockIdx.y * 128;
  const int tid = threadIdx.x;
  const int nt = tid >> 4;       // 0..15
  const int ot = tid & 15;       // 0..15
  const int mat = ot >> 3;       // 0=mu, 1=lv
  const int on0 = (ot & 7) * 8;  // 0..56

  float acc[8][8];
#pragma unroll
  for (int i = 0; i < 8; i++)
#pragma unroll
    for (int j = 0; j < 8; j++) acc[i][j] = 0.f;

  for (int k0 = 0; k0 < CIN; k0 += KC) {
    {
      const int kk = (tid & 7) * 4;
      const int nb = tid >> 3;  // 0..31
#pragma unroll
      for (int i = 0; i < 4; i++) {
        const int n = nb + i * 32;
        const int gn = n0 + n;
        float4 v = make_float4(0.f, 0.f, 0.f, 0.f);
        if (gn < N) v = *(const float4*)&f[(size_t)gn * CIN + k0 + kk];
        Fl[(kk + 0) * FLD + n] = v.x;
        Fl[(kk + 1) * FLD + n] = v.y;
        Fl[(kk + 2) * FLD + n] = v.z;
        Fl[(kk + 3) * FLD + n] = v.w;
      }
    }
    {
      const int oc = (tid & 15) * 4;
#pragma unroll
      for (int i = 0; i < 2; i++) {
        const int kr = (tid >> 4) + i * 16;
        float4 va = *(const float4*)&Wa[((size_t)r * CIN + k0 + kr) * 64 + oc];
        float4 vb = *(const float4*)&Wb[((size_t)r * CIN + k0 + kr) * 64 + oc];
        *(float4*)&Wl[0][kr * WLD + oc] = va;
        *(float4*)&Wl[1][kr * WLD + oc] = vb;
      }
    }
    __syncthreads();

#pragma unroll 4
    for (int kk = 0; kk < KC; kk++) {
      float4 fA = *(const float4*)&Fl[kk * FLD + nt * 8];
      float4 fB = *(const float4*)&Fl[kk * FLD + nt * 8 + 4];
      float4 wA = *(const float4*)&Wl[mat][kk * WLD + on0];
      float4 wB = *(const float4*)&Wl[mat][kk * WLD + on0 + 4];
      float fv[8] = {fA.x, fA.y, fA.z, fA.w, fB.x, fB.y, fB.z, fB.w};
      float wv[8] = {wA.x, wA.y, wA.z, wA.w, wB.x, wB.y, wB.z, wB.w};
#pragma unroll
      for (int i = 0; i < 8; i++)
#pragma unroll
        for (int j = 0; j < 8; j++) acc[i][j] = fmaf(fv[i], wv[j], acc[i][j]);
    }
    __syncthreads();
  }

  const float* qsel = mat ? qb : qa;
  const float* ksel = mat ? kb : ka;
  float qv[8], kv[8];
#pragma unroll
  for (int j = 0; j < 8; j++) {
    qv[j] = qsel[on0 + j];
    kv[j] = ksel[on0 + j];
  }

#pragma unroll
  for (int i = 0; i < 8; i++) {
    const int gn = n0 + nt * 8 + i;
    const bool valid = gn < N;
    if (valid) {
      float* dst = &t2[((size_t)r * N + gn) * 128 + mat * 64 + on0];
      *(float4*)dst = make_float4(acc[i][0], acc[i][1], acc[i][2], acc[i][3]);
      *(float4*)(dst + 4) =
          make_float4(acc[i][4], acc[i][5], acc[i][6], acc[i][7]);
    }
    float vq = 0.f, vk = 0.f;
#pragma unroll
    for (int j = 0; j < 8; j++) {
      vq = fmaf(acc[i][j], qv[j], vq);
      vk = fmaf(acc[i][j], kv[j], vk);
    }
#pragma unroll
    for (int d = 1; d < 8; d <<= 1) {  // reduce over ot&7 (lane bits 0-2)
      vq += __shfl_xor(vq, d, 64);
      vk += __shfl_xor(vk, d, 64);
    }
    if ((ot & 7) == 0 && valid) {
      aq2[(size_t)(mat * 8 + r) * N + gn] = vq;
      ak2[(size_t)(mat * 8 + r) * N + gn] = vk;
    }
  }
}

// ---------------------------------------------------------------------------
// Layer-1 aggregate: two-pass dedup softmax, ALL-LANES-ACTIVE form.
// Every __shfl executes with all 64 lanes active: edge loads are clamped
// (edges[beg+min(j,deg-1)]) and validity handled by SELECT, never by branch.
// aqw loaded unconditionally via clamped index so its register is always
// valid cross-lane (fixes the r4-r6 UB: shfl from inactive source lanes).
// ---------------------------------------------------------------------------
__global__ __launch_bounds__(256) void aggregate_kernel(
    const int* __restrict__ row_ptr, const int* __restrict__ edges,
    const float* __restrict__ t, const float* __restrict__ aq,
    const float* __restrict__ ak, const float* __restrict__ bias,
    float* __restrict__ out, int N) {
  const int tid = threadIdx.x;
  const int w = tid >> 6, o = tid & 63;
  int wid = blockIdx.x * 4 + w;
  const bool valid = wid < N;
  if (!valid) wid = N - 1;
  const int beg = row_ptr[wid];
  const int end = valid ? row_ptr[wid + 1] : beg;
  const int deg = end - beg;

  // every lane holds a valid aq value; lane o supplies aq[(o&7)][wid]
  const float aqw = aq[(size_t)(o & 7) * N + wid];

  // pass A: true max (all lanes active at every shfl)
  float m = -1e30f;
  for (int base = 0; base < deg; base += 64) {
    const int j = base + o;
    const int packed = edges[beg + min(j, deg - 1)];
    const int src = packed & 0xFFFF;
    const int rr = packed >> 16;
    float x = __shfl(aqw, rr, 64) + ak[rr * N + src];
    x = (x >= 0.f) ? x : NEG_SLOPE * x;
    m = fmaxf(m, (j < deg) ? x : -1e30f);
  }
#pragma unroll
  for (int d = 1; d < 64; d <<= 1) m = fmaxf(m, __shfl_xor(m, d, 64));

  // pass B: p once per edge (select-predicated), broadcast + coalesced gather
  float s = 0.f, acc = 0.f;
  for (int base = 0; base < deg; base += 64) {
    const int j = base + o;
    const int gcount = min(64, deg - base);
    const int packed = edges[beg + min(j, deg - 1)];
    const int src = packed & 0xFFFF;
    const int rr = packed >> 16;
    const int idx = rr * N + src;
    float x = __shfl(aqw, rr, 64) + ak[idx];
    x = (x >= 0.f) ? x : NEG_SLOPE * x;
    const float p = (j < deg) ? __expf(x - m) : 0.f;
    s += p;
    for (int u = 0; u < gcount; u++) {
      const float pu = __shfl(p, u, 64);
      const int iu = __shfl(idx, u, 64);
      acc = fmaf(pu, t[(size_t)iu * 64 + o], acc);  // coalesced 256B row
    }
  }
#pragma unroll
  for (int d = 1; d < 64; d <<= 1) s += __shfl_xor(s, d, 64);

  if (valid) {
    const float res = acc / (s + 1e-16f) + bias[o];
    out[(size_t)wid * 64 + o] = fmaxf(res, 0.f);
  }
}

// ---------------------------------------------------------------------------
// Fused mu+lv aggregate (all-lanes-active two-pass) + final linears.
// ---------------------------------------------------------------------------
__global__ __launch_bounds__(256) void aggregate2_kernel(
    const int* __restrict__ row_ptr, const int* __restrict__ edges,
    const float* __restrict__ t2, const float* __restrict__ aq2,
    const float* __restrict__ ak2, const float* __restrict__ bmu,
    const float* __restrict__ blv, const float* __restrict__ Wm,
    const float* __restrict__ bm, const float* __restrict__ Wlin,
    const float* __restrict__ bl, float* __restrict__ out_mu,
    float* __restrict__ out_ls, int N) {
  __shared__ float WmL[2048];
  __shared__ float WlL[2048];
  __shared__ float bL[64];
  __shared__ float hL[4][130];
  const int tid = threadIdx.x;
  for (int i = tid; i < 2048; i += 256) {
    WmL[i] = Wm[i];
    WlL[i] = Wlin[i];
  }
  if (tid < 32) {
    bL[tid] = bm[tid];
    bL[32 + tid] = bl[tid];
  }
  __syncthreads();

  const int w = tid >> 6, o = tid & 63;
  int wid = blockIdx.x * 4 + w;
  const bool valid = wid < N;
  if (!valid) wid = N - 1;
  const int beg = row_ptr[wid];
  const int end = valid ? row_ptr[wid + 1] : beg;
  const int deg = end - beg;

  // lane o supplies aq2[(o&15)][wid]; shfl sources 0..15 always valid
  const float aqw = aq2[(size_t)(o & 15) * N + wid];

  // pass A: max (both mats), all lanes active
  float m0 = -1e30f, m1 = -1e30f;
  for (int base = 0; base < deg; base += 64) {
    const int j = base + o;
    const int packed = edges[beg + min(j, deg - 1)];
    const int src = packed & 0xFFFF;
    const int rr = packed >> 16;
    const int idx = rr * N + src;
    float x0 = __shfl(aqw, rr, 64) + ak2[idx];
    float x1 = __shfl(aqw, 8 + rr, 64) + ak2[idx + 8 * N];
    x0 = (x0 >= 0.f) ? x0 : NEG_SLOPE * x0;
    x1 = (x1 >= 0.f) ? x1 : NEG_SLOPE * x1;
    m0 = fmaxf(m0, (j < deg) ? x0 : -1e30f);
    m1 = fmaxf(m1, (j < deg) ? x1 : -1e30f);
  }
#pragma unroll
  for (int d = 1; d < 64; d <<= 1) {
    m0 = fmaxf(m0, __shfl_xor(m0, d, 64));
    m1 = fmaxf(m1, __shfl_xor(m1, d, 64));
  }

  // pass B
  float s0 = 0.f, s1 = 0.f, acc0 = 0.f, acc1 = 0.f;
  for (int base = 0; base < deg; base += 64) {
    const int j = base + o;
    const int gcount = min(64, deg - base);
    const int packed = edges[beg + min(j, deg - 1)];
    const int src = packed & 0xFFFF;
    const int rr = packed >> 16;
    const int idx = rr * N + src;
    float x0 = __shfl(aqw, rr, 64) + ak2[idx];
    float x1 = __shfl(aqw, 8 + rr, 64) + ak2[idx + 8 * N];
    x0 = (x0 >= 0.f) ? x0 : NEG_SLOPE * x0;
    x1 = (x1 >= 0.f) ? x1 : NEG_SLOPE * x1;
    const float p0 = (j < deg) ? __expf(x0 - m0) : 0.f;
    const float p1 = (j < deg) ? __expf(x1 - m1) : 0.f;
    s0 += p0;
    s1 += p1;
    for (int u = 0; u < gcount; u++) {
      const float pu0 = __shfl(p0, u, 64);
      const float pu1 = __shfl(p1, u, 64);
      const int iu = __shfl(idx, u, 64);
      const float* trow = t2 + (size_t)iu * 128;
      acc0 = fmaf(pu0, trow[o], acc0);       // coalesced 256B
      acc1 = fmaf(pu1, trow[64 + o], acc1);  // coalesced 256B
    }
  }
#pragma unroll
  for (int d = 1; d < 64; d <<= 1) {
    s0 += __shfl_xor(s0, d, 64);
    s1 += __shfl_xor(s1, d, 64);
  }

  const float h0 = fmaxf(acc0 / (s0 + 1e-16f) + bmu[o], 0.f);
  const float h1 = fmaxf(acc1 / (s1 + 1e-16f) + blv[o], 0.f);
  hL[w][o] = h0;
  hL[w][64 + o] = h1;
  __syncthreads();

  // lanes 0-31: mu linear; lanes 32-63: lv linear (0.5x for logstd)
  const float* hrow = &hL[w][(o >= 32) ? 64 : 0];
  const float* WL = (o >= 32) ? WlL : WmL;
  const int j = o & 31;
  float acc = 0.f;
#pragma unroll 8
  for (int c = 0; c < 64; c++) acc = fmaf(hrow[c], WL[c * 32 + j], acc);
  if (valid) {
    if (o < 32)
      out_mu[(size_t)wid * 32 + j] = acc + bL[j];
    else
      out_ls[(size_t)wid * 32 + j] = (acc + bL[32 + j]) * 0.5f;
  }
}

// ---------------------------------------------------------------------------
extern "C" void kernel_launch(void* const* d_in, const int* in_sizes, int n_in,
                              void* d_out, int out_size, void* d_ws,
                              size_t ws_size, hipStream_t stream) {
  const float* x = (const float*)d_in[0];
  const int* edge_index = (const int*)d_in[1];
  const int* edge_type = (const int*)d_in[2];
  const float* W1 = (const float*)d_in[3];
  const float* q1 = (const float*)d_in[4];
  const float* k1 = (const float*)d_in[5];
  const float* b1 = (const float*)d_in[6];
  const float* Wmu = (const float*)d_in[7];
  const float* qmu = (const float*)d_in[8];
  const float* kmu = (const float*)d_in[9];
  const float* bmu = (const float*)d_in[10];
  const float* Wlv = (const float*)d_in[11];
  const float* qlv = (const float*)d_in[12];
  const float* klv = (const float*)d_in[13];
  const float* blv = (const float*)d_in[14];
  const float* Wm = (const float*)d_in[15];
  const float* bm = (const float*)d_in[16];
  const float* Wl = (const float*)d_in[17];
  const float* bl = (const float*)d_in[18];

  const int N = in_sizes[0] / 128;         // 50000
  const int E = in_sizes[2];               // 1.6M
  const int R = in_sizes[3] / (128 * 64);  // 8

  float* out_mu = (float*)d_out;
  float* out_ls = (float*)d_out + (size_t)N * ODIM;

  char* wsp = (char*)d_ws;
  size_t off = 0;
  auto carve = [&](size_t bytes) {
    void* p = wsp + off;
    off += (bytes + 255) & ~(size_t)255;
    return p;
  };

  float* t2 = (float*)carve((size_t)R * N * 128 * sizeof(float));  // 204.8 MB
  float* aq2 = (float*)carve((size_t)2 * R * N * sizeof(float));
  float* ak2 = (float*)carve((size_t)2 * R * N * sizeof(float));
  float* hidden = (float*)carve((size_t)N * HDIM * sizeof(float));
  int* deg = (int*)carve((size_t)N * sizeof(int));
  int* fill = (int*)carve((size_t)N * sizeof(int));
  int* row_ptr = (int*)carve((size_t)(N + 1) * sizeof(int));
  int* bsum = (int*)carve(256 * sizeof(int));
  int* edges = (int*)carve((size_t)E * sizeof(int));

  const int* e_src = edge_index;
  const int* e_dst = edge_index + E;

  // ---- CSR build ----
  hipMemsetAsync(deg, 0, (size_t)N * sizeof(int), stream);
  hipMemsetAsync(fill, 0, (size_t)N * sizeof(int), stream);
  count_deg_kernel<<<(E + 255) / 256, 256, 0, stream>>>(e_dst, deg, E);
  const int nchunk = (N + SCHUNK - 1) / SCHUNK;
  scan_p1<<<nchunk, 256, 0, stream>>>(deg, bsum, N);
  scan_p2<<<1, 64, 0, stream>>>(bsum, nchunk);
  scan_p3<<<nchunk, 256, 0, stream>>>(deg, bsum, row_ptr, N);
  scatter_kernel<<<(E + 255) / 256, 256, 0, stream>>>(e_src, e_dst, edge_type,
                                                      row_ptr, fill, edges, E);

  const int tiles256 = (N + 255) / 256;
  const int agg_blocks = (N + 3) / 4;

  // ---- layer 1: IN=128 -> H=64 (t2 buffer reused as [R][N][64]) ----
  transform_kernel<128><<<dim3(R, tiles256), 256, 0, stream>>>(
      x, W1, q1, k1, t2, aq2, ak2, N);
  aggregate_kernel<<<agg_blocks, 256, 0, stream>>>(row_ptr, edges, t2, aq2,
                                                   ak2, b1, hidden, N);

  // ---- fused conv_mu + conv_logvar + output linears ----
  const int tiles128 = (N + 127) / 128;
  transform2_kernel<<<dim3(R, tiles128), 256, 0, stream>>>(
      hidden, Wmu, Wlv, qmu, kmu, qlv, klv, t2, aq2, ak2, N);
  aggregate2_kernel<<<agg_blocks, 256, 0, stream>>>(row_ptr, edges, t2, aq2,
                                                    ak2, bmu, blv, Wm, bm, Wl,
                                                    bl, out_mu, out_ls, N);
}

// Round 8
// 669.145 us; speedup vs baseline: 1.1441x; 1.1441x over previous
//
#include <hip/hip_runtime.h>
#include <cstdint>

// N=50000 nodes, E=1.6M edges, IN=128, H=64, OUT=32, R=8
#define HDIM 64
#define ODIM 32
#define NEG_SLOPE 0.2f
#define SCHUNK 2048

__device__ __forceinline__ unsigned f2bf_rne(float f) {
  unsigned u = __float_as_uint(f);
  return (u + 0x7FFFu + ((u >> 16) & 1u)) >> 16;  // round-to-nearest-even
}

// ---------------------------------------------------------------------------
// CSR build
// ---------------------------------------------------------------------------
__global__ __launch_bounds__(256) void count_deg_kernel(
    const int* __restrict__ dst, int* __restrict__ deg, int E) {
  int e = blockIdx.x * 256 + threadIdx.x;
  if (e < E) atomicAdd(&deg[dst[e]], 1);
}

__global__ __launch_bounds__(256) void scan_p1(const int* __restrict__ deg,
                                               int* __restrict__ bsum, int n) {
  int base = blockIdx.x * SCHUNK + threadIdx.x * 8;
  int s = 0;
#pragma unroll
  for (int j = 0; j < 8; j++) {
    int i = base + j;
    if (i < n) s += deg[i];
  }
#pragma unroll
  for (int d = 1; d < 64; d <<= 1) s += __shfl_xor(s, d, 64);
  __shared__ int ws[4];
  if ((threadIdx.x & 63) == 0) ws[threadIdx.x >> 6] = s;
  __syncthreads();
  if (threadIdx.x == 0) bsum[blockIdx.x] = ws[0] + ws[1] + ws[2] + ws[3];
}

__global__ void scan_p2(int* bsum, int nb) {
  int i = threadIdx.x;
  int v = (i < nb) ? bsum[i] : 0;
  int orig = v;
#pragma unroll
  for (int d = 1; d < 64; d <<= 1) {
    int up = __shfl_up(v, d, 64);
    if (i >= d) v += up;
  }
  if (i < nb) bsum[i] = v - orig;
}

__global__ __launch_bounds__(256) void scan_p3(const int* __restrict__ deg,
                                               const int* __restrict__ bsum,
                                               int* __restrict__ row_ptr,
                                               int n) {
  int base = blockIdx.x * SCHUNK + threadIdx.x * 8;
  int vals[8];
  int s = 0;
#pragma unroll
  for (int j = 0; j < 8; j++) {
    int i = base + j;
    vals[j] = (i < n) ? deg[i] : 0;
    s += vals[j];
  }
  int lane = threadIdx.x & 63, w = threadIdx.x >> 6;
  int v = s;
#pragma unroll
  for (int d = 1; d < 64; d <<= 1) {
    int up = __shfl_up(v, d, 64);
    if (lane >= d) v += up;
  }
  __shared__ int wsum[4];
  if (lane == 63) wsum[w] = v;
  __syncthreads();
  int woff = 0;
#pragma unroll
  for (int i = 0; i < 4; i++) woff += (i < w) ? wsum[i] : 0;
  int off = bsum[blockIdx.x] + woff + v - s;
#pragma unroll
  for (int j = 0; j < 8; j++) {
    int i = base + j;
    off += vals[j];
    if (i < n) row_ptr[i + 1] = off;
  }
  if (blockIdx.x == 0 && threadIdx.x == 0) row_ptr[0] = 0;
}

__global__ __launch_bounds__(256) void scatter_kernel(
    const int* __restrict__ src, const int* __restrict__ dst,
    const int* __restrict__ etype, const int* __restrict__ row_ptr,
    int* __restrict__ fill, int* __restrict__ edges, int E) {
  int e = blockIdx.x * 256 + threadIdx.x;
  if (e < E) {
    int d = dst[e];
    int pos = row_ptr[d] + atomicAdd(&fill[d], 1);
    edges[pos] = src[e] | (etype[e] << 16);  // N < 65536
  }
}

// ---------------------------------------------------------------------------
// Layer-1 transform (validated KC=32): t[r,n,:] = f[n,:] @ W[r] (+ aq/ak)
// ---------------------------------------------------------------------------
template <int CIN>
__global__ __launch_bounds__(256) void transform_kernel(
    const float* __restrict__ f, const float* __restrict__ W,
    const float* __restrict__ q, const float* __restrict__ k,
    float* __restrict__ t, float* __restrict__ aq, float* __restrict__ ak,
    int N) {
  constexpr int KC = 32;
  constexpr int FLD = 260;
  constexpr int WLD = 68;
  __shared__ float Fl[KC * FLD];
  __shared__ float Wl[KC * WLD];

  const int r = blockIdx.x;
  const int n0 = blockIdx.y * 256;
  const int tid = threadIdx.x;
  const int nt = tid >> 3;
  const int ot = tid & 7;
  const int on0 = ot * 8;

  float acc[8][8];
#pragma unroll
  for (int i = 0; i < 8; i++)
#pragma unroll
    for (int j = 0; j < 8; j++) acc[i][j] = 0.f;

  for (int k0 = 0; k0 < CIN; k0 += KC) {
    {
      const int kk = (tid & 7) * 4;
      const int nb = tid >> 3;
#pragma unroll
      for (int i = 0; i < 8; i++) {
        const int n = nb + i * 32;
        const int gn = n0 + n;
        float4 v = make_float4(0.f, 0.f, 0.f, 0.f);
        if (gn < N) v = *(const float4*)&f[(size_t)gn * CIN + k0 + kk];
        Fl[(kk + 0) * FLD + n] = v.x;
        Fl[(kk + 1) * FLD + n] = v.y;
        Fl[(kk + 2) * FLD + n] = v.z;
        Fl[(kk + 3) * FLD + n] = v.w;
      }
    }
    {
      const int oc = (tid & 15) * 4;
#pragma unroll
      for (int i = 0; i < 2; i++) {
        const int kr = (tid >> 4) + i * 16;
        float4 v = *(const float4*)&W[((size_t)r * CIN + k0 + kr) * 64 + oc];
        *(float4*)&Wl[kr * WLD + oc] = v;
      }
    }
    __syncthreads();

#pragma unroll 4
    for (int kk = 0; kk < KC; kk++) {
      float4 fA = *(const float4*)&Fl[kk * FLD + nt * 8];
      float4 fB = *(const float4*)&Fl[kk * FLD + nt * 8 + 4];
      float4 wA = *(const float4*)&Wl[kk * WLD + on0];
      float4 wB = *(const float4*)&Wl[kk * WLD + on0 + 4];
      float fv[8] = {fA.x, fA.y, fA.z, fA.w, fB.x, fB.y, fB.z, fB.w};
      float wv[8] = {wA.x, wA.y, wA.z, wA.w, wB.x, wB.y, wB.z, wB.w};
#pragma unroll
      for (int i = 0; i < 8; i++)
#pragma unroll
        for (int j = 0; j < 8; j++) acc[i][j] = fmaf(fv[i], wv[j], acc[i][j]);
    }
    __syncthreads();
  }

  float qv[8], kv[8];
#pragma unroll
  for (int j = 0; j < 8; j++) {
    qv[j] = q[on0 + j];
    kv[j] = k[on0 + j];
  }

#pragma unroll
  for (int i = 0; i < 8; i++) {
    const int gn = n0 + nt * 8 + i;
    const bool valid = gn < N;
    if (valid) {
      float* dst = &t[((size_t)r * N + gn) * 64 + on0];
      *(float4*)dst = make_float4(acc[i][0], acc[i][1], acc[i][2], acc[i][3]);
      *(float4*)(dst + 4) =
          make_float4(acc[i][4], acc[i][5], acc[i][6], acc[i][7]);
    }
    float vq = 0.f, vk = 0.f;
#pragma unroll
    for (int j = 0; j < 8; j++) {
      vq = fmaf(acc[i][j], qv[j], vq);
      vk = fmaf(acc[i][j], kv[j], vk);
    }
#pragma unroll
    for (int d = 1; d < 8; d <<= 1) {
      vq += __shfl_xor(vq, d, 64);
      vk += __shfl_xor(vk, d, 64);
    }
    if (ot == 0 && valid) {
      aq[(size_t)r * N + gn] = vq;
      ak[(size_t)r * N + gn] = vk;
    }
  }
}

// ---------------------------------------------------------------------------
// Fused mu+lv transform (KC=32). NEW: t2 stored as packed bf16x2 —
// t2p[(r*N+n)*64 + c] = bf16(mu_c) | bf16(lv_c)<<16. Partner-lane (^8)
// exchange (all lanes active) pairs the two matrices' values.
// aq2/ak2: [(mat*8+r)][N], fp32.
// ---------------------------------------------------------------------------
__global__ __launch_bounds__(256) void transform2_kernel(
    const float* __restrict__ f, const float* __restrict__ Wa,
    const float* __restrict__ Wb, const float* __restrict__ qa,
    const float* __restrict__ ka, const float* __restrict__ qb,
    const float* __restrict__ kb, unsigned* __restrict__ t2p,
    float* __restrict__ aq2, float* __restrict__ ak2, int N) {
  constexpr int CIN = 64, KC = 32;
  constexpr int FLD = 132;  // 128 + 4 pad
  constexpr int WLD = 68;
  __shared__ float Fl[KC * FLD];
  __shared__ float Wl[2][KC * WLD + 4];  // +4: offsets mat1 banks by 4

  const int r = blockIdx.x;
  const int n0 = blockIdx.y * 128;
  const int tid = threadIdx.x;
  const int nt = tid >> 4;       // 0..15
  const int ot = tid & 15;       // 0..15
  const int mat = ot >> 3;       // 0=mu, 1=lv
  const int on0 = (ot & 7) * 8;  // 0..56

  float acc[8][8];
#pragma unroll
  for (int i = 0; i < 8; i++)
#pragma unroll
    for (int j = 0; j < 8; j++) acc[i][j] = 0.f;

  for (int k0 = 0; k0 < CIN; k0 += KC) {
    {
      const int kk = (tid & 7) * 4;
      const int nb = tid >> 3;  // 0..31
#pragma unroll
      for (int i = 0; i < 4; i++) {
        const int n = nb + i * 32;
        const int gn = n0 + n;
        float4 v = make_float4(0.f, 0.f, 0.f, 0.f);
        if (gn < N) v = *(const float4*)&f[(size_t)gn * CIN + k0 + kk];
        Fl[(kk + 0) * FLD + n] = v.x;
        Fl[(kk + 1) * FLD + n] = v.y;
        Fl[(kk + 2) * FLD + n] = v.z;
        Fl[(kk + 3) * FLD + n] = v.w;
      }
    }
    {
      const int oc = (tid & 15) * 4;
#pragma unroll
      for (int i = 0; i < 2; i++) {
        const int kr = (tid >> 4) + i * 16;
        float4 va = *(const float4*)&Wa[((size_t)r * CIN + k0 + kr) * 64 + oc];
        float4 vb = *(const float4*)&Wb[((size_t)r * CIN + k0 + kr) * 64 + oc];
        *(float4*)&Wl[0][kr * WLD + oc] = va;
        *(float4*)&Wl[1][kr * WLD + oc] = vb;
      }
    }
    __syncthreads();

#pragma unroll 4
    for (int kk = 0; kk < KC; kk++) {
      float4 fA = *(const float4*)&Fl[kk * FLD + nt * 8];
      float4 fB = *(const float4*)&Fl[kk * FLD + nt * 8 + 4];
      float4 wA = *(const float4*)&Wl[mat][kk * WLD + on0];
      float4 wB = *(const float4*)&Wl[mat][kk * WLD + on0 + 4];
      float fv[8] = {fA.x, fA.y, fA.z, fA.w, fB.x, fB.y, fB.z, fB.w};
      float wv[8] = {wA.x, wA.y, wA.z, wA.w, wB.x, wB.y, wB.z, wB.w};
#pragma unroll
      for (int i = 0; i < 8; i++)
#pragma unroll
        for (int j = 0; j < 8; j++) acc[i][j] = fmaf(fv[i], wv[j], acc[i][j]);
    }
    __syncthreads();
  }

  const float* qsel = mat ? qb : qa;
  const float* ksel = mat ? kb : ka;
  float qv[8], kv[8];
#pragma unroll
  for (int j = 0; j < 8; j++) {
    qv[j] = qsel[on0 + j];
    kv[j] = ksel[on0 + j];
  }

#pragma unroll
  for (int i = 0; i < 8; i++) {
    const int gn = n0 + nt * 8 + i;
    const bool valid = gn < N;

    // pack mu|lv via partner-lane exchange (lane^8 flips mat; shfl is
    // unconditional -> all source lanes active)
    unsigned pk[8];
#pragma unroll
    for (int j = 0; j < 8; j++) {
      const float other = __shfl_xor(acc[i][j], 8, 64);
      pk[j] = f2bf_rne(acc[i][j]) | (f2bf_rne(other) << 16);
    }
    if (mat == 0 && valid) {
      unsigned* dst = t2p + ((size_t)r * N + gn) * 64 + on0;
      *(uint4*)dst = make_uint4(pk[0], pk[1], pk[2], pk[3]);
      *(uint4*)(dst + 4) = make_uint4(pk[4], pk[5], pk[6], pk[7]);
    }

    float vq = 0.f, vk = 0.f;
#pragma unroll
    for (int j = 0; j < 8; j++) {
      vq = fmaf(acc[i][j], qv[j], vq);
      vk = fmaf(acc[i][j], kv[j], vk);
    }
#pragma unroll
    for (int d = 1; d < 8; d <<= 1) {  // reduce over ot&7 (lane bits 0-2)
      vq += __shfl_xor(vq, d, 64);
      vk += __shfl_xor(vk, d, 64);
    }
    if ((ot & 7) == 0 && valid) {
      aq2[(size_t)(mat * 8 + r) * N + gn] = vq;
      ak2[(size_t)(mat * 8 + r) * N + gn] = vk;
    }
  }
}

// ---------------------------------------------------------------------------
// Layer-1 aggregate: two-pass dedup softmax, all-lanes-active, with
// unroll-4 batched gather (4 independent 256B loads in flight).
// ---------------------------------------------------------------------------
__global__ __launch_bounds__(256) void aggregate_kernel(
    const int* __restrict__ row_ptr, const int* __restrict__ edges,
    const float* __restrict__ t, const float* __restrict__ aq,
    const float* __restrict__ ak, const float* __restrict__ bias,
    float* __restrict__ out, int N) {
  const int tid = threadIdx.x;
  const int w = tid >> 6, o = tid & 63;
  int wid = blockIdx.x * 4 + w;
  const bool valid = wid < N;
  if (!valid) wid = N - 1;
  const int beg = row_ptr[wid];
  const int end = valid ? row_ptr[wid + 1] : beg;
  const int deg = end - beg;

  const float aqw = aq[(size_t)(o & 7) * N + wid];

  // pass A: true max (all lanes active at every shfl)
  float m = -1e30f;
  for (int base = 0; base < deg; base += 64) {
    const int j = base + o;
    const int packed = edges[beg + min(j, deg - 1)];
    const int src = packed & 0xFFFF;
    const int rr = packed >> 16;
    float x = __shfl(aqw, rr, 64) + ak[rr * N + src];
    x = (x >= 0.f) ? x : NEG_SLOPE * x;
    m = fmaxf(m, (j < deg) ? x : -1e30f);
  }
#pragma unroll
  for (int d = 1; d < 64; d <<= 1) m = fmaxf(m, __shfl_xor(m, d, 64));

  // pass B: p once per edge; unroll-4 broadcast+gather (p=0 lanes have
  // clamped-but-valid idx, so over-run iterations add exactly 0)
  float s = 0.f, acc = 0.f;
  for (int base = 0; base < deg; base += 64) {
    const int j = base + o;
    const int gcount = min(64, deg - base);
    const int packed = edges[beg + min(j, deg - 1)];
    const int src = packed & 0xFFFF;
    const int rr = packed >> 16;
    const int idx = rr * N + src;
    float x = __shfl(aqw, rr, 64) + ak[idx];
    x = (x >= 0.f) ? x : NEG_SLOPE * x;
    const float p = (j < deg) ? __expf(x - m) : 0.f;
    s += p;
    const int g4 = (gcount + 3) & ~3;
    for (int u = 0; u < g4; u += 4) {
      float pu[4];
      int iu[4];
#pragma unroll
      for (int v = 0; v < 4; v++) {
        pu[v] = __shfl(p, u + v, 64);
        iu[v] = __shfl(idx, u + v, 64);
      }
      float tv[4];
#pragma unroll
      for (int v = 0; v < 4; v++) tv[v] = t[(size_t)iu[v] * 64 + o];
#pragma unroll
      for (int v = 0; v < 4; v++) acc = fmaf(pu[v], tv[v], acc);
    }
  }
#pragma unroll
  for (int d = 1; d < 64; d <<= 1) s += __shfl_xor(s, d, 64);

  if (valid) {
    const float res = acc / (s + 1e-16f) + bias[o];
    out[(size_t)wid * 64 + o] = fmaxf(res, 0.f);
  }
}

// ---------------------------------------------------------------------------
// Fused mu+lv aggregate: bf16x2-packed t2 (ONE 256B gather per edge feeds
// both accumulators), unroll-4 MLP, + final linears in epilogue.
// ---------------------------------------------------------------------------
__global__ __launch_bounds__(256) void aggregate2_kernel(
    const int* __restrict__ row_ptr, const int* __restrict__ edges,
    const unsigned* __restrict__ t2p, const float* __restrict__ aq2,
    const float* __restrict__ ak2, const float* __restrict__ bmu,
    const float* __restrict__ blv, const float* __restrict__ Wm,
    const float* __restrict__ bm, const float* __restrict__ Wlin,
    const float* __restrict__ bl, float* __restrict__ out_mu,
    float* __restrict__ out_ls, int N) {
  __shared__ float WmL[2048];
  __shared__ float WlL[2048];
  __shared__ float bL[64];
  __shared__ float hL[4][130];
  const int tid = threadIdx.x;
  for (int i = tid; i < 2048; i += 256) {
    WmL[i] = Wm[i];
    WlL[i] = Wlin[i];
  }
  if (tid < 32) {
    bL[tid] = bm[tid];
    bL[32 + tid] = bl[tid];
  }
  __syncthreads();

  const int w = tid >> 6, o = tid & 63;
  int wid = blockIdx.x * 4 + w;
  const bool valid = wid < N;
  if (!valid) wid = N - 1;
  const int beg = row_ptr[wid];
  const int end = valid ? row_ptr[wid + 1] : beg;
  const int deg = end - beg;

  const float aqw = aq2[(size_t)(o & 15) * N + wid];

  // pass A: max (both mats), all lanes active
  float m0 = -1e30f, m1 = -1e30f;
  for (int base = 0; base < deg; base += 64) {
    const int j = base + o;
    const int packed = edges[beg + min(j, deg - 1)];
    const int src = packed & 0xFFFF;
    const int rr = packed >> 16;
    const int idx = rr * N + src;
    float x0 = __shfl(aqw, rr, 64) + ak2[idx];
    float x1 = __shfl(aqw, 8 + rr, 64) + ak2[idx + 8 * N];
    x0 = (x0 >= 0.f) ? x0 : NEG_SLOPE * x0;
    x1 = (x1 >= 0.f) ? x1 : NEG_SLOPE * x1;
    m0 = fmaxf(m0, (j < deg) ? x0 : -1e30f);
    m1 = fmaxf(m1, (j < deg) ? x1 : -1e30f);
  }
#pragma unroll
  for (int d = 1; d < 64; d <<= 1) {
    m0 = fmaxf(m0, __shfl_xor(m0, d, 64));
    m1 = fmaxf(m1, __shfl_xor(m1, d, 64));
  }

  // pass B
  float s0 = 0.f, s1 = 0.f, acc0 = 0.f, acc1 = 0.f;
  for (int base = 0; base < deg; base += 64) {
    const int j = base + o;
    const int gcount = min(64, deg - base);
    const int packed = edges[beg + min(j, deg - 1)];
    const int src = packed & 0xFFFF;
    const int rr = packed >> 16;
    const int idx = rr * N + src;
    float x0 = __shfl(aqw, rr, 64) + ak2[idx];
    float x1 = __shfl(aqw, 8 + rr, 64) + ak2[idx + 8 * N];
    x0 = (x0 >= 0.f) ? x0 : NEG_SLOPE * x0;
    x1 = (x1 >= 0.f) ? x1 : NEG_SLOPE * x1;
    const float p0 = (j < deg) ? __expf(x0 - m0) : 0.f;
    const float p1 = (j < deg) ? __expf(x1 - m1) : 0.f;
    s0 += p0;
    s1 += p1;
    const int g4 = (gcount + 3) & ~3;
    for (int u = 0; u < g4; u += 4) {
      float pu0[4], pu1[4];
      int iu[4];
#pragma unroll
      for (int v = 0; v < 4; v++) {
        pu0[v] = __shfl(p0, u + v, 64);
        pu1[v] = __shfl(p1, u + v, 64);
        iu[v] = __shfl(idx, u + v, 64);
      }
      unsigned pk[4];
#pragma unroll
      for (int v = 0; v < 4; v++) pk[v] = t2p[(size_t)iu[v] * 64 + o];
#pragma unroll
      for (int v = 0; v < 4; v++) {
        acc0 = fmaf(pu0[v], __uint_as_float(pk[v] << 16), acc0);
        acc1 = fmaf(pu1[v], __uint_as_float(pk[v] & 0xFFFF0000u), acc1);
      }
    }
  }
#pragma unroll
  for (int d = 1; d < 64; d <<= 1) {
    s0 += __shfl_xor(s0, d, 64);
    s1 += __shfl_xor(s1, d, 64);
  }

  const float h0 = fmaxf(acc0 / (s0 + 1e-16f) + bmu[o], 0.f);
  const float h1 = fmaxf(acc1 / (s1 + 1e-16f) + blv[o], 0.f);
  hL[w][o] = h0;
  hL[w][64 + o] = h1;
  __syncthreads();

  // lanes 0-31: mu linear; lanes 32-63: lv linear (0.5x for logstd)
  const float* hrow = &hL[w][(o >= 32) ? 64 : 0];
  const float* WL = (o >= 32) ? WlL : WmL;
  const int j = o & 31;
  float acc = 0.f;
#pragma unroll 8
  for (int c = 0; c < 64; c++) acc = fmaf(hrow[c], WL[c * 32 + j], acc);
  if (valid) {
    if (o < 32)
      out_mu[(size_t)wid * 32 + j] = acc + bL[j];
    else
      out_ls[(size_t)wid * 32 + j] = (acc + bL[32 + j]) * 0.5f;
  }
}

// ---------------------------------------------------------------------------
extern "C" void kernel_launch(void* const* d_in, const int* in_sizes, int n_in,
                              void* d_out, int out_size, void* d_ws,
                              size_t ws_size, hipStream_t stream) {
  const float* x = (const float*)d_in[0];
  const int* edge_index = (const int*)d_in[1];
  const int* edge_type = (const int*)d_in[2];
  const float* W1 = (const float*)d_in[3];
  const float* q1 = (const float*)d_in[4];
  const float* k1 = (const float*)d_in[5];
  const float* b1 = (const float*)d_in[6];
  const float* Wmu = (const float*)d_in[7];
  const float* qmu = (const float*)d_in[8];
  const float* kmu = (const float*)d_in[9];
  const float* bmu = (const float*)d_in[10];
  const float* Wlv = (const float*)d_in[11];
  const float* qlv = (const float*)d_in[12];
  const float* klv = (const float*)d_in[13];
  const float* blv = (const float*)d_in[14];
  const float* Wm = (const float*)d_in[15];
  const float* bm = (const float*)d_in[16];
  const float* Wl = (const float*)d_in[17];
  const float* bl = (const float*)d_in[18];

  const int N = in_sizes[0] / 128;         // 50000
  const int E = in_sizes[2];               // 1.6M
  const int R = in_sizes[3] / (128 * 64);  // 8

  float* out_mu = (float*)d_out;
  float* out_ls = (float*)d_out + (size_t)N * ODIM;

  char* wsp = (char*)d_ws;
  size_t off = 0;
  auto carve = [&](size_t bytes) {
    void* p = wsp + off;
    off += (bytes + 255) & ~(size_t)255;
    return p;
  };

  // one 102.4 MB buffer: layer-1 t (fp32 [R][N][64]) then t2p (bf16x2 packed)
  void* tbuf = carve((size_t)R * N * 64 * sizeof(float));
  float* t1 = (float*)tbuf;
  unsigned* t2p = (unsigned*)tbuf;
  float* aq2 = (float*)carve((size_t)2 * R * N * sizeof(float));
  float* ak2 = (float*)carve((size_t)2 * R * N * sizeof(float));
  float* hidden = (float*)carve((size_t)N * HDIM * sizeof(float));
  int* deg = (int*)carve((size_t)N * sizeof(int));
  int* fill = (int*)carve((size_t)N * sizeof(int));
  int* row_ptr = (int*)carve((size_t)(N + 1) * sizeof(int));
  int* bsum = (int*)carve(256 * sizeof(int));
  int* edges = (int*)carve((size_t)E * sizeof(int));

  const int* e_src = edge_index;
  const int* e_dst = edge_index + E;

  // ---- CSR build ----
  hipMemsetAsync(deg, 0, (size_t)N * sizeof(int), stream);
  hipMemsetAsync(fill, 0, (size_t)N * sizeof(int), stream);
  count_deg_kernel<<<(E + 255) / 256, 256, 0, stream>>>(e_dst, deg, E);
  const int nchunk = (N + SCHUNK - 1) / SCHUNK;
  scan_p1<<<nchunk, 256, 0, stream>>>(deg, bsum, N);
  scan_p2<<<1, 64, 0, stream>>>(bsum, nchunk);
  scan_p3<<<nchunk, 256, 0, stream>>>(deg, bsum, row_ptr, N);
  scatter_kernel<<<(E + 255) / 256, 256, 0, stream>>>(e_src, e_dst, edge_type,
                                                      row_ptr, fill, edges, E);

  const int tiles256 = (N + 255) / 256;
  const int agg_blocks = (N + 3) / 4;

  // ---- layer 1: IN=128 -> H=64 (fp32 t) ----
  transform_kernel<128><<<dim3(R, tiles256), 256, 0, stream>>>(
      x, W1, q1, k1, t1, aq2, ak2, N);
  aggregate_kernel<<<agg_blocks, 256, 0, stream>>>(row_ptr, edges, t1, aq2,
                                                   ak2, b1, hidden, N);

  // ---- fused conv_mu + conv_logvar (bf16x2 t2) + output linears ----
  const int tiles128 = (N + 127) / 128;
  transform2_kernel<<<dim3(R, tiles128), 256, 0, stream>>>(
      hidden, Wmu, Wlv, qmu, kmu, qlv, klv, t2p, aq2, ak2, N);
  aggregate2_kernel<<<agg_blocks, 256, 0, stream>>>(row_ptr, edges, t2p, aq2,
                                                    ak2, bmu, blv, Wm, bm, Wl,
                                                    bl, out_mu, out_ls, N);
}

// Round 9
// 632.777 us; speedup vs baseline: 1.2098x; 1.0575x over previous
//
#include <hip/hip_runtime.h>
#include <cstdint>

// N=50000 nodes, E=1.6M edges, IN=128, H=64, OUT=32, R=8
#define HDIM 64
#define ODIM 32
#define NEG_SLOPE 0.2f
#define SCHUNK 2048

__device__ __forceinline__ unsigned f2bf_rne(float f) {
  unsigned u = __float_as_uint(f);
  return (u + 0x7FFFu + ((u >> 16) & 1u)) >> 16;  // round-to-nearest-even
}

// ---------------------------------------------------------------------------
// CSR build
// ---------------------------------------------------------------------------
__global__ __launch_bounds__(256) void count_deg_kernel(
    const int* __restrict__ dst, int* __restrict__ deg, int E) {
  int e = blockIdx.x * 256 + threadIdx.x;
  if (e < E) atomicAdd(&deg[dst[e]], 1);
}

__global__ __launch_bounds__(256) void scan_p1(const int* __restrict__ deg,
                                               int* __restrict__ bsum, int n) {
  int base = blockIdx.x * SCHUNK + threadIdx.x * 8;
  int s = 0;
#pragma unroll
  for (int j = 0; j < 8; j++) {
    int i = base + j;
    if (i < n) s += deg[i];
  }
#pragma unroll
  for (int d = 1; d < 64; d <<= 1) s += __shfl_xor(s, d, 64);
  __shared__ int ws[4];
  if ((threadIdx.x & 63) == 0) ws[threadIdx.x >> 6] = s;
  __syncthreads();
  if (threadIdx.x == 0) bsum[blockIdx.x] = ws[0] + ws[1] + ws[2] + ws[3];
}

__global__ void scan_p2(int* bsum, int nb) {
  int i = threadIdx.x;
  int v = (i < nb) ? bsum[i] : 0;
  int orig = v;
#pragma unroll
  for (int d = 1; d < 64; d <<= 1) {
    int up = __shfl_up(v, d, 64);
    if (i >= d) v += up;
  }
  if (i < nb) bsum[i] = v - orig;
}

__global__ __launch_bounds__(256) void scan_p3(const int* __restrict__ deg,
                                               const int* __restrict__ bsum,
                                               int* __restrict__ row_ptr,
                                               int n) {
  int base = blockIdx.x * SCHUNK + threadIdx.x * 8;
  int vals[8];
  int s = 0;
#pragma unroll
  for (int j = 0; j < 8; j++) {
    int i = base + j;
    vals[j] = (i < n) ? deg[i] : 0;
    s += vals[j];
  }
  int lane = threadIdx.x & 63, w = threadIdx.x >> 6;
  int v = s;
#pragma unroll
  for (int d = 1; d < 64; d <<= 1) {
    int up = __shfl_up(v, d, 64);
    if (lane >= d) v += up;
  }
  __shared__ int wsum[4];
  if (lane == 63) wsum[w] = v;
  __syncthreads();
  int woff = 0;
#pragma unroll
  for (int i = 0; i < 4; i++) woff += (i < w) ? wsum[i] : 0;
  int off = bsum[blockIdx.x] + woff + v - s;
#pragma unroll
  for (int j = 0; j < 8; j++) {
    int i = base + j;
    off += vals[j];
    if (i < n) row_ptr[i + 1] = off;
  }
  if (blockIdx.x == 0 && threadIdx.x == 0) row_ptr[0] = 0;
}

__global__ __launch_bounds__(256) void scatter_kernel(
    const int* __restrict__ src, const int* __restrict__ dst,
    const int* __restrict__ etype, const int* __restrict__ row_ptr,
    int* __restrict__ fill, int* __restrict__ edges, int E) {
  int e = blockIdx.x * 256 + threadIdx.x;
  if (e < E) {
    int d = dst[e];
    int pos = row_ptr[d] + atomicAdd(&fill[d], 1);
    edges[pos] = src[e] | (etype[e] << 16);  // N < 65536
  }
}

// ---------------------------------------------------------------------------
// Layer-1 transform, KC=16 (21 KB LDS -> 7 blocks/CU; k-order identical to
// KC=32 so results are bit-exact vs the validated round-3 kernel).
// NEW: t stored as bf16 (halves WRITE + the aggregate's gather bytes).
// ---------------------------------------------------------------------------
template <int CIN>
__global__ __launch_bounds__(256) void transform_kernel(
    const float* __restrict__ f, const float* __restrict__ W,
    const float* __restrict__ q, const float* __restrict__ k,
    unsigned short* __restrict__ tb, float* __restrict__ aq,
    float* __restrict__ ak, int N) {
  constexpr int KC = 16;
  constexpr int FLD = 260;
  constexpr int WLD = 68;
  __shared__ float Fl[KC * FLD];  // 16.6 KB
  __shared__ float Wl[KC * WLD];  //  4.4 KB

  const int r = blockIdx.x;
  const int n0 = blockIdx.y * 256;
  const int tid = threadIdx.x;
  const int nt = tid >> 3;
  const int ot = tid & 7;
  const int on0 = ot * 8;

  float acc[8][8];
#pragma unroll
  for (int i = 0; i < 8; i++)
#pragma unroll
    for (int j = 0; j < 8; j++) acc[i][j] = 0.f;

  for (int k0 = 0; k0 < CIN; k0 += KC) {
    {
      const int kk = (tid & 3) * 4;
      const int nb = tid >> 2;  // 0..63
#pragma unroll
      for (int i = 0; i < 4; i++) {
        const int n = nb + i * 64;
        const int gn = n0 + n;
        float4 v = make_float4(0.f, 0.f, 0.f, 0.f);
        if (gn < N) v = *(const float4*)&f[(size_t)gn * CIN + k0 + kk];
        Fl[(kk + 0) * FLD + n] = v.x;
        Fl[(kk + 1) * FLD + n] = v.y;
        Fl[(kk + 2) * FLD + n] = v.z;
        Fl[(kk + 3) * FLD + n] = v.w;
      }
    }
    {
      const int oc = (tid & 15) * 4;
      const int kr = tid >> 4;  // 0..15
      float4 v = *(const float4*)&W[((size_t)r * CIN + k0 + kr) * 64 + oc];
      *(float4*)&Wl[kr * WLD + oc] = v;
    }
    __syncthreads();

#pragma unroll 4
    for (int kk = 0; kk < KC; kk++) {
      float4 fA = *(const float4*)&Fl[kk * FLD + nt * 8];
      float4 fB = *(const float4*)&Fl[kk * FLD + nt * 8 + 4];
      float4 wA = *(const float4*)&Wl[kk * WLD + on0];
      float4 wB = *(const float4*)&Wl[kk * WLD + on0 + 4];
      float fv[8] = {fA.x, fA.y, fA.z, fA.w, fB.x, fB.y, fB.z, fB.w};
      float wv[8] = {wA.x, wA.y, wA.z, wA.w, wB.x, wB.y, wB.z, wB.w};
#pragma unroll
      for (int i = 0; i < 8; i++)
#pragma unroll
        for (int j = 0; j < 8; j++) acc[i][j] = fmaf(fv[i], wv[j], acc[i][j]);
    }
    __syncthreads();
  }

  float qv[8], kv[8];
#pragma unroll
  for (int j = 0; j < 8; j++) {
    qv[j] = q[on0 + j];
    kv[j] = k[on0 + j];
  }

#pragma unroll
  for (int i = 0; i < 8; i++) {
    const int gn = n0 + nt * 8 + i;
    const bool valid = gn < N;
    if (valid) {
      // pack 8 channels as bf16 pairs -> uint4 (16B aligned: on0*2 % 16 == 0)
      unsigned pk[4];
#pragma unroll
      for (int j = 0; j < 4; j++)
        pk[j] = f2bf_rne(acc[i][2 * j]) | (f2bf_rne(acc[i][2 * j + 1]) << 16);
      *(uint4*)&tb[((size_t)r * N + gn) * 64 + on0] =
          make_uint4(pk[0], pk[1], pk[2], pk[3]);
    }
    float vq = 0.f, vk = 0.f;
#pragma unroll
    for (int j = 0; j < 8; j++) {
      vq = fmaf(acc[i][j], qv[j], vq);
      vk = fmaf(acc[i][j], kv[j], vk);
    }
#pragma unroll
    for (int d = 1; d < 8; d <<= 1) {
      vq += __shfl_xor(vq, d, 64);
      vk += __shfl_xor(vk, d, 64);
    }
    if (ot == 0 && valid) {
      aq[(size_t)r * N + gn] = vq;
      ak[(size_t)r * N + gn] = vk;
    }
  }
}

// ---------------------------------------------------------------------------
// Fused mu+lv transform, KC=16 (17 KB LDS). t2 packed bf16x2 (mu|lv) via
// partner-lane (^8) exchange. aq2/ak2: [(mat*8+r)][N], fp32.
// ---------------------------------------------------------------------------
__global__ __launch_bounds__(256) void transform2_kernel(
    const float* __restrict__ f, const float* __restrict__ Wa,
    const float* __restrict__ Wb, const float* __restrict__ qa,
    const float* __restrict__ ka, const float* __restrict__ qb,
    const float* __restrict__ kb, unsigned* __restrict__ t2p,
    float* __restrict__ aq2, float* __restrict__ ak2, int N) {
  constexpr int CIN = 64, KC = 16;
  constexpr int FLD = 132;  // 128 + 4 pad
  constexpr int WLD = 68;
  __shared__ float Fl[KC * FLD];
  __shared__ float Wl[2][KC * WLD + 4];

  const int r = blockIdx.x;
  const int n0 = blockIdx.y * 128;
  const int tid = threadIdx.x;
  const int nt = tid >> 4;       // 0..15
  const int ot = tid & 15;       // 0..15
  const int mat = ot >> 3;       // 0=mu, 1=lv
  const int on0 = (ot & 7) * 8;  // 0..56

  float acc[8][8];
#pragma unroll
  for (int i = 0; i < 8; i++)
#pragma unroll
    for (int j = 0; j < 8; j++) acc[i][j] = 0.f;

  for (int k0 = 0; k0 < CIN; k0 += KC) {
    {
      const int kk = (tid & 3) * 4;
      const int nb = tid >> 2;  // 0..63
#pragma unroll
      for (int i = 0; i < 2; i++) {
        const int n = nb + i * 64;
        const int gn = n0 + n;
        float4 v = make_float4(0.f, 0.f, 0.f, 0.f);
        if (gn < N) v = *(const float4*)&f[(size_t)gn * CIN + k0 + kk];
        Fl[(kk + 0) * FLD + n] = v.x;
        Fl[(kk + 1) * FLD + n] = v.y;
        Fl[(kk + 2) * FLD + n] = v.z;
        Fl[(kk + 3) * FLD + n] = v.w;
      }
    }
    {
      const int oc = (tid & 15) * 4;
      const int kr = tid >> 4;  // 0..15
      float4 va = *(const float4*)&Wa[((size_t)r * CIN + k0 + kr) * 64 + oc];
      float4 vb = *(const float4*)&Wb[((size_t)r * CIN + k0 + kr) * 64 + oc];
      *(float4*)&Wl[0][kr * WLD + oc] = va;
      *(float4*)&Wl[1][kr * WLD + oc] = vb;
    }
    __syncthreads();

#pragma unroll 4
    for (int kk = 0; kk < KC; kk++) {
      float4 fA = *(const float4*)&Fl[kk * FLD + nt * 8];
      float4 fB = *(const float4*)&Fl[kk * FLD + nt * 8 + 4];
      float4 wA = *(const float4*)&Wl[mat][kk * WLD + on0];
      float4 wB = *(const float4*)&Wl[mat][kk * WLD + on0 + 4];
      float fv[8] = {fA.x, fA.y, fA.z, fA.w, fB.x, fB.y, fB.z, fB.w};
      float wv[8] = {wA.x, wA.y, wA.z, wA.w, wB.x, wB.y, wB.z, wB.w};
#pragma unroll
      for (int i = 0; i < 8; i++)
#pragma unroll
        for (int j = 0; j < 8; j++) acc[i][j] = fmaf(fv[i], wv[j], acc[i][j]);
    }
    __syncthreads();
  }

  const float* qsel = mat ? qb : qa;
  const float* ksel = mat ? kb : ka;
  float qv[8], kv[8];
#pragma unroll
  for (int j = 0; j < 8; j++) {
    qv[j] = qsel[on0 + j];
    kv[j] = ksel[on0 + j];
  }

#pragma unroll
  for (int i = 0; i < 8; i++) {
    const int gn = n0 + nt * 8 + i;
    const bool valid = gn < N;

    unsigned pk[8];
#pragma unroll
    for (int j = 0; j < 8; j++) {
      const float other = __shfl_xor(acc[i][j], 8, 64);  // all lanes active
      pk[j] = f2bf_rne(acc[i][j]) | (f2bf_rne(other) << 16);
    }
    if (mat == 0 && valid) {
      unsigned* dst = t2p + ((size_t)r * N + gn) * 64 + on0;
      *(uint4*)dst = make_uint4(pk[0], pk[1], pk[2], pk[3]);
      *(uint4*)(dst + 4) = make_uint4(pk[4], pk[5], pk[6], pk[7]);
    }

    float vq = 0.f, vk = 0.f;
#pragma unroll
    for (int j = 0; j < 8; j++) {
      vq = fmaf(acc[i][j], qv[j], vq);
      vk = fmaf(acc[i][j], kv[j], vk);
    }
#pragma unroll
    for (int d = 1; d < 8; d <<= 1) {
      vq += __shfl_xor(vq, d, 64);
      vk += __shfl_xor(vk, d, 64);
    }
    if ((ot & 7) == 0 && valid) {
      aq2[(size_t)(mat * 8 + r) * N + gn] = vq;
      ak2[(size_t)(mat * 8 + r) * N + gn] = vk;
    }
  }
}

// ---------------------------------------------------------------------------
// Layer-1 aggregate: two-pass dedup softmax, all-lanes-active shfl, bf16 t,
// unroll-4 batched gather.
// ---------------------------------------------------------------------------
__global__ __launch_bounds__(256) void aggregate_kernel(
    const int* __restrict__ row_ptr, const int* __restrict__ edges,
    const unsigned short* __restrict__ tb, const float* __restrict__ aq,
    const float* __restrict__ ak, const float* __restrict__ bias,
    float* __restrict__ out, int N) {
  const int tid = threadIdx.x;
  const int w = tid >> 6, o = tid & 63;
  int wid = blockIdx.x * 4 + w;
  const bool valid = wid < N;
  if (!valid) wid = N - 1;
  const int beg = row_ptr[wid];
  const int end = valid ? row_ptr[wid + 1] : beg;
  const int deg = end - beg;

  const float aqw = aq[(size_t)(o & 7) * N + wid];

  // pass A: true max (all lanes active at every shfl)
  float m = -1e30f;
  for (int base = 0; base < deg; base += 64) {
    const int j = base + o;
    const int packed = edges[beg + min(j, deg - 1)];
    const int src = packed & 0xFFFF;
    const int rr = packed >> 16;
    float x = __shfl(aqw, rr, 64) + ak[rr * N + src];
    x = (x >= 0.f) ? x : NEG_SLOPE * x;
    m = fmaxf(m, (j < deg) ? x : -1e30f);
  }
#pragma unroll
  for (int d = 1; d < 64; d <<= 1) m = fmaxf(m, __shfl_xor(m, d, 64));

  // pass B: p once per edge; unroll-4 broadcast + coalesced bf16 gather
  float s = 0.f, acc = 0.f;
  for (int base = 0; base < deg; base += 64) {
    const int j = base + o;
    const int gcount = min(64, deg - base);
    const int packed = edges[beg + min(j, deg - 1)];
    const int src = packed & 0xFFFF;
    const int rr = packed >> 16;
    const int idx = rr * N + src;
    float x = __shfl(aqw, rr, 64) + ak[idx];
    x = (x >= 0.f) ? x : NEG_SLOPE * x;
    const float p = (j < deg) ? __expf(x - m) : 0.f;
    s += p;
    const int g4 = (gcount + 3) & ~3;
    for (int u = 0; u < g4; u += 4) {
      float pu[4];
      int iu[4];
#pragma unroll
      for (int v = 0; v < 4; v++) {
        pu[v] = __shfl(p, u + v, 64);
        iu[v] = __shfl(idx, u + v, 64);
      }
      unsigned short tv[4];
#pragma unroll
      for (int v = 0; v < 4; v++) tv[v] = tb[(size_t)iu[v] * 64 + o];
#pragma unroll
      for (int v = 0; v < 4; v++)
        acc = fmaf(pu[v], __uint_as_float((unsigned)tv[v] << 16), acc);
    }
  }
#pragma unroll
  for (int d = 1; d < 64; d <<= 1) s += __shfl_xor(s, d, 64);

  if (valid) {
    const float res = acc / (s + 1e-16f) + bias[o];
    out[(size_t)wid * 64 + o] = fmaxf(res, 0.f);
  }
}

// ---------------------------------------------------------------------------
// Fused mu+lv aggregate: bf16x2-packed t2 (one 256B gather per edge feeds
// both accumulators), unroll-4 MLP, + final linears in epilogue.
// ---------------------------------------------------------------------------
__global__ __launch_bounds__(256) void aggregate2_kernel(
    const int* __restrict__ row_ptr, const int* __restrict__ edges,
    const unsigned* __restrict__ t2p, const float* __restrict__ aq2,
    const float* __restrict__ ak2, const float* __restrict__ bmu,
    const float* __restrict__ blv, const float* __restrict__ Wm,
    const float* __restrict__ bm, const float* __restrict__ Wlin,
    const float* __restrict__ bl, float* __restrict__ out_mu,
    float* __restrict__ out_ls, int N) {
  __shared__ float WmL[2048];
  __shared__ float WlL[2048];
  __shared__ float bL[64];
  __shared__ float hL[4][130];
  const int tid = threadIdx.x;
  for (int i = tid; i < 2048; i += 256) {
    WmL[i] = Wm[i];
    WlL[i] = Wlin[i];
  }
  if (tid < 32) {
    bL[tid] = bm[tid];
    bL[32 + tid] = bl[tid];
  }
  __syncthreads();

  const int w = tid >> 6, o = tid & 63;
  int wid = blockIdx.x * 4 + w;
  const bool valid = wid < N;
  if (!valid) wid = N - 1;
  const int beg = row_ptr[wid];
  const int end = valid ? row_ptr[wid + 1] : beg;
  const int deg = end - beg;

  const float aqw = aq2[(size_t)(o & 15) * N + wid];

  // pass A: max (both mats), all lanes active
  float m0 = -1e30f, m1 = -1e30f;
  for (int base = 0; base < deg; base += 64) {
    const int j = base + o;
    const int packed = edges[beg + min(j, deg - 1)];
    const int src = packed & 0xFFFF;
    const int rr = packed >> 16;
    const int idx = rr * N + src;
    float x0 = __shfl(aqw, rr, 64) + ak2[idx];
    float x1 = __shfl(aqw, 8 + rr, 64) + ak2[idx + 8 * N];
    x0 = (x0 >= 0.f) ? x0 : NEG_SLOPE * x0;
    x1 = (x1 >= 0.f) ? x1 : NEG_SLOPE * x1;
    m0 = fmaxf(m0, (j < deg) ? x0 : -1e30f);
    m1 = fmaxf(m1, (j < deg) ? x1 : -1e30f);
  }
#pragma unroll
  for (int d = 1; d < 64; d <<= 1) {
    m0 = fmaxf(m0, __shfl_xor(m0, d, 64));
    m1 = fmaxf(m1, __shfl_xor(m1, d, 64));
  }

  // pass B
  float s0 = 0.f, s1 = 0.f, acc0 = 0.f, acc1 = 0.f;
  for (int base = 0; base < deg; base += 64) {
    const int j = base + o;
    const int gcount = min(64, deg - base);
    const int packed = edges[beg + min(j, deg - 1)];
    const int src = packed & 0xFFFF;
    const int rr = packed >> 16;
    const int idx = rr * N + src;
    float x0 = __shfl(aqw, rr, 64) + ak2[idx];
    float x1 = __shfl(aqw, 8 + rr, 64) + ak2[idx + 8 * N];
    x0 = (x0 >= 0.f) ? x0 : NEG_SLOPE * x0;
    x1 = (x1 >= 0.f) ? x1 : NEG_SLOPE * x1;
    const float p0 = (j < deg) ? __expf(x0 - m0) : 0.f;
    const float p1 = (j < deg) ? __expf(x1 - m1) : 0.f;
    s0 += p0;
    s1 += p1;
    const int g4 = (gcount + 3) & ~3;
    for (int u = 0; u < g4; u += 4) {
      float pu0[4], pu1[4];
      int iu[4];
#pragma unroll
      for (int v = 0; v < 4; v++) {
        pu0[v] = __shfl(p0, u + v, 64);
        pu1[v] = __shfl(p1, u + v, 64);
        iu[v] = __shfl(idx, u + v, 64);
      }
      unsigned pk[4];
#pragma unroll
      for (int v = 0; v < 4; v++) pk[v] = t2p[(size_t)iu[v] * 64 + o];
#pragma unroll
      for (int v = 0; v < 4; v++) {
        acc0 = fmaf(pu0[v], __uint_as_float(pk[v] << 16), acc0);
        acc1 = fmaf(pu1[v], __uint_as_float(pk[v] & 0xFFFF0000u), acc1);
      }
    }
  }
#pragma unroll
  for (int d = 1; d < 64; d <<= 1) {
    s0 += __shfl_xor(s0, d, 64);
    s1 += __shfl_xor(s1, d, 64);
  }

  const float h0 = fmaxf(acc0 / (s0 + 1e-16f) + bmu[o], 0.f);
  const float h1 = fmaxf(acc1 / (s1 + 1e-16f) + blv[o], 0.f);
  hL[w][o] = h0;
  hL[w][64 + o] = h1;
  __syncthreads();

  // lanes 0-31: mu linear; lanes 32-63: lv linear (0.5x for logstd)
  const float* hrow = &hL[w][(o >= 32) ? 64 : 0];
  const float* WL = (o >= 32) ? WlL : WmL;
  const int j = o & 31;
  float acc = 0.f;
#pragma unroll 8
  for (int c = 0; c < 64; c++) acc = fmaf(hrow[c], WL[c * 32 + j], acc);
  if (valid) {
    if (o < 32)
      out_mu[(size_t)wid * 32 + j] = acc + bL[j];
    else
      out_ls[(size_t)wid * 32 + j] = (acc + bL[32 + j]) * 0.5f;
  }
}

// ---------------------------------------------------------------------------
extern "C" void kernel_launch(void* const* d_in, const int* in_sizes, int n_in,
                              void* d_out, int out_size, void* d_ws,
                              size_t ws_size, hipStream_t stream) {
  const float* x = (const float*)d_in[0];
  const int* edge_index = (const int*)d_in[1];
  const int* edge_type = (const int*)d_in[2];
  const float* W1 = (const float*)d_in[3];
  const float* q1 = (const float*)d_in[4];
  const float* k1 = (const float*)d_in[5];
  const float* b1 = (const float*)d_in[6];
  const float* Wmu = (const float*)d_in[7];
  const float* qmu = (const float*)d_in[8];
  const float* kmu = (const float*)d_in[9];
  const float* bmu = (const float*)d_in[10];
  const float* Wlv = (const float*)d_in[11];
  const float* qlv = (const float*)d_in[12];
  const float* klv = (const float*)d_in[13];
  const float* blv = (const float*)d_in[14];
  const float* Wm = (const float*)d_in[15];
  const float* bm = (const float*)d_in[16];
  const float* Wl = (const float*)d_in[17];
  const float* bl = (const float*)d_in[18];

  const int N = in_sizes[0] / 128;         // 50000
  const int E = in_sizes[2];               // 1.6M
  const int R = in_sizes[3] / (128 * 64);  // 8

  float* out_mu = (float*)d_out;
  float* out_ls = (float*)d_out + (size_t)N * ODIM;

  char* wsp = (char*)d_ws;
  size_t off = 0;
  auto carve = [&](size_t bytes) {
    void* p = wsp + off;
    off += (bytes + 255) & ~(size_t)255;
    return p;
  };

  // t buffer: layer-1 bf16 [R][N][64] (51.2 MB) then reused as bf16x2-packed
  // t2 (102.4 MB) — carve the max of the two
  void* tbuf = carve((size_t)R * N * 64 * sizeof(unsigned));
  unsigned short* t1b = (unsigned short*)tbuf;
  unsigned* t2p = (unsigned*)tbuf;
  float* aq2 = (float*)carve((size_t)2 * R * N * sizeof(float));
  float* ak2 = (float*)carve((size_t)2 * R * N * sizeof(float));
  float* hidden = (float*)carve((size_t)N * HDIM * sizeof(float));
  int* deg = (int*)carve((size_t)N * sizeof(int));
  int* fill = (int*)carve((size_t)N * sizeof(int));
  int* row_ptr = (int*)carve((size_t)(N + 1) * sizeof(int));
  int* bsum = (int*)carve(256 * sizeof(int));
  int* edges = (int*)carve((size_t)E * sizeof(int));

  const int* e_src = edge_index;
  const int* e_dst = edge_index + E;

  // ---- CSR build ----
  hipMemsetAsync(deg, 0, (size_t)N * sizeof(int), stream);
  hipMemsetAsync(fill, 0, (size_t)N * sizeof(int), stream);
  count_deg_kernel<<<(E + 255) / 256, 256, 0, stream>>>(e_dst, deg, E);
  const int nchunk = (N + SCHUNK - 1) / SCHUNK;
  scan_p1<<<nchunk, 256, 0, stream>>>(deg, bsum, N);
  scan_p2<<<1, 64, 0, stream>>>(bsum, nchunk);
  scan_p3<<<nchunk, 256, 0, stream>>>(deg, bsum, row_ptr, N);
  scatter_kernel<<<(E + 255) / 256, 256, 0, stream>>>(e_src, e_dst, edge_type,
                                                      row_ptr, fill, edges, E);

  const int tiles256 = (N + 255) / 256;
  const int agg_blocks = (N + 3) / 4;

  // ---- layer 1: IN=128 -> H=64 (bf16 t) ----
  transform_kernel<128><<<dim3(R, tiles256), 256, 0, stream>>>(
      x, W1, q1, k1, t1b, aq2, ak2, N);
  aggregate_kernel<<<agg_blocks, 256, 0, stream>>>(row_ptr, edges, t1b, aq2,
                                                   ak2, b1, hidden, N);

  // ---- fused conv_mu + conv_logvar (bf16x2 t2) + output linears ----
  const int tiles128 = (N + 127) / 128;
  transform2_kernel<<<dim3(R, tiles128), 256, 0, stream>>>(
      hidden, Wmu, Wlv, qmu, kmu, qlv, klv, t2p, aq2, ak2, N);
  aggregate2_kernel<<<agg_blocks, 256, 0, stream>>>(row_ptr, edges, t2p, aq2,
                                                    ak2, bmu, blv, Wm, bm, Wl,
                                                    bl, out_mu, out_ls, N);
}